// Round 11
// baseline (462.818 us; speedup 1.0000x reference)
//
#include <hip/hip_runtime.h>

#define N_NODES 32000
#define NPG     1000
#define BSZ     32
#define NEDGE   512000
#define H       128
#define NL      3
#define NR      8
#define NW      1152    // 8*128 rel cols + 128 self cols
#define NBIN2   262144  // 32768 dst bins x 8 contention-splitting sub-bins

typedef __attribute__((ext_vector_type(8))) short short8;
typedef __attribute__((ext_vector_type(4))) float float4v;

__device__ __forceinline__ float bf2f(unsigned short u) {
  union { unsigned int i; float f; } v;
  v.i = ((unsigned int)u) << 16;
  return v.f;
}
__device__ __forceinline__ unsigned short f2bf(float f) {
  union { float f; unsigned int i; } v;
  v.f = f;
  unsigned int x = v.i;
  return (unsigned short)((x + 0x7FFFu + ((x >> 16) & 1u)) >> 16);  // RNE
}

// ---------------- fused prep: cvtX | cvtB | per-(dst,sub) count | graph hist ----------
__global__ __launch_bounds__(256) void k_prep(
    const float* __restrict__ x, const float* __restrict__ W_rel,
    const float* __restrict__ W_self, const int* __restrict__ dst,
    const int* __restrict__ graph_id,
    unsigned short* __restrict__ hb, unsigned short* __restrict__ Bt,
    int* __restrict__ cnt, int* __restrict__ gcount)
{
  const int b = blockIdx.x, t = threadIdx.x;
  if (b < 4000) {                       // x fp32 -> h0 bf16
    const size_t i = ((size_t)b * 256 + t) * 4;
    float4 v = *(const float4*)(x + i);
    ushort4 u = { f2bf(v.x), f2bf(v.y), f2bf(v.z), f2bf(v.w) };
    *(ushort4*)(hb + i) = u;
  } else if (b < 5728) {                // weights -> Bt9[l][n=0..1151][k] (transposed)
    const int g = (b - 4000) * 256 + t;  // 0..442367
    const int k = g & 127;
    const int n = (g >> 7) % NW;
    const int l = g / (NW * H);
    float v = (n < 1024) ? W_rel[(((size_t)l * NR + (n >> 7)) * H + k) * H + (n & 127)]
                         : W_self[((size_t)l * H + k) * H + (n - 1024)];
    Bt[(size_t)l * (NW * H) + (size_t)n * H + k] = f2bf(v);
  } else if (b < 7728) {                // per-(dst,sub) edge counts, 8-way de-contended
    const int bb = b - 5728;            // 0..1999
    const int e = bb * 256 + t;
    atomicAdd(&cnt[dst[e] * 8 + (bb & 7)], 1);
  } else {                              // graph histogram (125 blocks)
    __shared__ int hist[BSZ];
    if (t < BSZ) hist[t] = 0;
    __syncthreads();
    const int n = (b - 7728) * 256 + t;
    if (n < N_NODES) atomicAdd(&hist[graph_id[n]], 1);
    __syncthreads();
    if (t < BSZ) { int v = hist[t]; if (v) atomicAdd(&gcount[t], v); }
  }
}

// ---------------- single-dispatch exclusive scan over NBIN2 bins ----------------
// 1024 threads x 256 bins each, streamed twice from L2; LDS Hillis-Steele over partials.
__global__ __launch_bounds__(1024) void k_scan1(const int* __restrict__ cnt,
                                                int* __restrict__ row_ptr2,
                                                int* __restrict__ cursor) {
  __shared__ int lds[1024];
  const int t = threadIdx.x;
  const int base = t * 256;
  int s = 0;
  for (int i = 0; i < 64; ++i) {
    int4 v = *(const int4*)(cnt + base + i * 4);
    s += v.x + v.y + v.z + v.w;
  }
  lds[t] = s;
  __syncthreads();
  for (int off = 1; off < 1024; off <<= 1) {
    int val = (t >= off) ? lds[t - off] : 0;
    __syncthreads();
    lds[t] += val;
    __syncthreads();
  }
  int run = lds[t] - s;   // exclusive prefix
  for (int i = 0; i < 64; ++i) {
    int4 v = *(const int4*)(cnt + base + i * 4);
    int4 w;
    w.x = run; run += v.x;
    w.y = run; run += v.y;
    w.z = run; run += v.z;
    w.w = run; run += v.w;
    *(int4*)(row_ptr2 + base + i * 4) = w;
    *(int4*)(cursor   + base + i * 4) = w;
  }
}

// ---------------- fill: edge_off[p] = src*1152 + etype*128, grouped by (dst,sub) ----
__global__ void k_fill(const int* __restrict__ src, const int* __restrict__ dst,
                       const int* __restrict__ etype, int* __restrict__ cursor,
                       int* __restrict__ edge_off) {
  int e = blockIdx.x * blockDim.x + threadIdx.x;
  if (e < NEDGE) {
    int p = atomicAdd(&cursor[dst[e] * 8 + (blockIdx.x & 7)], 1);
    edge_off[p] = src[e] * NW + etype[e] * H;
  }
}

// ---------------- GEMM9: G = h @ [Wrel(8) | Wself]  (M=32000, K=128, N=1152) --------
__global__ __launch_bounds__(256) void k_gemm9(
    const unsigned short* __restrict__ Ah,   // [32000,128] bf16
    const unsigned short* __restrict__ Bt,   // [1152,128]  bf16
    unsigned short* __restrict__ G)          // [32000,1152] bf16
{
  __shared__ unsigned short lds_a[128 * 136];
  __shared__ unsigned short lds_b[128 * 136];
  const int tid  = threadIdx.x;
  const int wave = tid >> 6, lane = tid & 63;
  const int l15 = lane & 15, quad = lane >> 4;
  const int m0 = blockIdx.x * 128;
  const int n0 = blockIdx.y * 128;
  const int mb = (wave & 1) * 64;
  const int nb = (wave >> 1) * 64;

  #pragma unroll
  for (int s = 0; s < 8; ++s) {
    int f  = s * 256 + tid;
    int m  = f >> 4;
    int ko = (f & 15) * 8;
    *(uint4*)(lds_a + m * 136 + ko) = *(const uint4*)(Ah + (size_t)(m0 + m) * H + ko);
    *(uint4*)(lds_b + m * 136 + ko) = *(const uint4*)(Bt + (size_t)(n0 + m) * H + ko);
  }
  __syncthreads();

  float4v acc[4][4];
  #pragma unroll
  for (int i = 0; i < 4; ++i)
    #pragma unroll
    for (int j = 0; j < 4; ++j) acc[i][j] = (float4v){0.f, 0.f, 0.f, 0.f};

  #pragma unroll
  for (int ks = 0; ks < 4; ++ks) {
    const int ko = ks * 32 + quad * 8;
    short8 afr[4], bfr[4];
    #pragma unroll
    for (int i = 0; i < 4; ++i)
      afr[i] = *(const short8*)(lds_a + (mb + i * 16 + l15) * 136 + ko);
    #pragma unroll
    for (int j = 0; j < 4; ++j)
      bfr[j] = *(const short8*)(lds_b + (nb + j * 16 + l15) * 136 + ko);
    #pragma unroll
    for (int i = 0; i < 4; ++i)
      #pragma unroll
      for (int j = 0; j < 4; ++j)
        acc[i][j] = __builtin_amdgcn_mfma_f32_16x16x32_bf16(afr[i], bfr[j], acc[i][j], 0, 0, 0);
  }

  // repack -> coalesced uint4 stores. D: row=quad*4+r, col=l15.
  __syncthreads();
  #pragma unroll
  for (int i = 0; i < 4; ++i)
    #pragma unroll
    for (int j = 0; j < 4; ++j)
      #pragma unroll
      for (int r = 0; r < 4; ++r)
        lds_a[(mb + i * 16 + quad * 4 + r) * 136 + nb + j * 16 + l15] = f2bf(acc[i][j][r]);
  __syncthreads();
  #pragma unroll
  for (int s = 0; s < 8; ++s) {
    int f  = s * 256 + tid;
    int m  = f >> 4;
    int ko = (f & 15) * 8;
    *(uint4*)(G + (size_t)(m0 + m) * NW + n0 + ko) = *(const uint4*)(lds_a + m * 136 + ko);
  }
}

// ---------------- edge gather: half-wave edge split, uint2 row loads --------
// h_next[n] = relu(G[n,1024:] + sum_e G[edge_off[e], :128])
// per-node edge range = [row_ptr2[n*8], row_ptr2[n*8+8]) (dst-major sub-bins).
__global__ __launch_bounds__(256) void k_gather(
    const unsigned short* __restrict__ G, const int* __restrict__ row_ptr2,
    const int* __restrict__ edge_off, unsigned short* __restrict__ Hnext)
{
  const int node = blockIdx.x * 4 + (threadIdx.x >> 6);
  const int lane = threadIdx.x & 63;
  const int half = lane >> 5;
  const int li   = lane & 31;
  const int c0   = li * 4;
  const int beg = row_ptr2[node << 3];
  const int end = row_ptr2[(node << 3) + 8];
  float s0 = 0.f, s1 = 0.f, s2 = 0.f, s3 = 0.f;
  if (half == 0) {   // self term counted once
    uint2 u = *(const uint2*)(G + (size_t)node * NW + 1024 + c0);
    s0 = bf2f((unsigned short)(u.x & 0xffff));
    s1 = bf2f((unsigned short)(u.x >> 16));
    s2 = bf2f((unsigned short)(u.y & 0xffff));
    s3 = bf2f((unsigned short)(u.y >> 16));
  }
#define ACC4(u) { \
    s0 += bf2f((unsigned short)((u).x & 0xffff)); \
    s1 += bf2f((unsigned short)((u).x >> 16));    \
    s2 += bf2f((unsigned short)((u).y & 0xffff)); \
    s3 += bf2f((unsigned short)((u).y >> 16)); }
  int e = beg + half;
  for (; e + 6 < end; e += 8) {   // 4 rows in flight per half = 8 per wave
    int o0 = edge_off[e],     o1 = edge_off[e + 2];
    int o2 = edge_off[e + 4], o3 = edge_off[e + 6];
    uint2 u0 = *(const uint2*)(G + o0 + c0);
    uint2 u1 = *(const uint2*)(G + o1 + c0);
    uint2 u2 = *(const uint2*)(G + o2 + c0);
    uint2 u3 = *(const uint2*)(G + o3 + c0);
    ACC4(u0) ACC4(u1) ACC4(u2) ACC4(u3)
  }
  for (; e < end; e += 2) {
    int o = edge_off[e];
    uint2 u = *(const uint2*)(G + o + c0);
    ACC4(u)
  }
#undef ACC4
  s0 += __shfl_xor(s0, 32);
  s1 += __shfl_xor(s1, 32);
  s2 += __shfl_xor(s2, 32);
  s3 += __shfl_xor(s3, 32);
  if (half == 0) {
    uint2 w;
    w.x = (unsigned int)f2bf(fmaxf(s0, 0.f)) | ((unsigned int)f2bf(fmaxf(s1, 0.f)) << 16);
    w.y = (unsigned int)f2bf(fmaxf(s2, 0.f)) | ((unsigned int)f2bf(fmaxf(s3, 0.f)) << 16);
    *(uint2*)(Hnext + (size_t)node * H + c0) = w;
  }
}

// ---------------- per-graph partial mean from bf16 h (8-way split + float atomics) ----
__global__ void k_gmean(const unsigned short* __restrict__ hb, float* __restrict__ gmean)
{
  const int g = blockIdx.x, l = blockIdx.y, c = blockIdx.z, t = threadIdx.x;  // 64
  const unsigned short* base =
      hb + ((size_t)(l + 1) * N_NODES + (size_t)g * NPG + (size_t)c * (NPG / 8)) * H + t * 2;
  float sx = 0.f, sy = 0.f;
  for (int i = 0; i < 125; ++i) {
    unsigned int u = *(const unsigned int*)(base + (size_t)i * H);
    sx += bf2f((unsigned short)(u & 0xffff));
    sy += bf2f((unsigned short)(u >> 16));
  }
  float* gp = gmean + (size_t)g * (NL * H) + l * H + t * 2;
  atomicAdd(gp, sx);
  atomicAdd(gp + 1, sy);
}

// ---------------- readout ----------------
__global__ __launch_bounds__(128) void k_final(
    const unsigned short* __restrict__ hb, const float* __restrict__ gmean,
    const int* __restrict__ gcount,
    const float* __restrict__ rel_tb, const float* __restrict__ Zn,
    const float* __restrict__ projW, const float* __restrict__ projB,
    const float* __restrict__ fcW, const float* __restrict__ fcB,
    const float* __restrict__ repSeq,
    const int* __restrict__ head_ids, const int* __restrict__ tail_ids,
    const int* __restrict__ rel_lab, float* __restrict__ out)
{
  const int b = blockIdx.x;
  const int o = threadIdx.x;   // 128
  __shared__ float gm[384], hf[384], tf[384];
  __shared__ float go[128], ho[128], t_o[128], re[128], rs[128], sv[128];
  __shared__ float lg[128], pr[128], red[128], att[3];

  const int hid = head_ids[b], tlid = tail_ids[b], rl = rel_lab[b];
  const float cinv = 1.f / (float)gcount[b];
  #pragma unroll
  for (int l = 0; l < NL; ++l) {
    gm[l * H + o] = gmean[(size_t)b * (NL * H) + l * H + o] * cinv;
    hf[l * H + o] = bf2f(hb[((size_t)(l + 1) * N_NODES + hid) * H + o]);
    tf[l * H + o] = bf2f(hb[((size_t)(l + 1) * N_NODES + tlid) * H + o]);
  }
  re[o] = rel_tb[rl * H + o];
  rs[o] = repSeq[b * H + o];
  __syncthreads();

  float pb = projB[o];
  float sg = pb, sh = pb, st = pb;
  for (int i = 0; i < NL * H; ++i) {
    float wv = projW[i * H + o];
    sg = fmaf(gm[i], wv, sg);
    sh = fmaf(hf[i], wv, sh);
    st = fmaf(tf[i], wv, st);
  }
  go[o] = (sg > 0.f) ? sg : 0.01f * sg;
  ho[o] = sh;
  t_o[o] = st;
  __syncthreads();

  {
    const int k = o & 63;
    const float* v = (o < 64) ? ho : t_o;
    float s = 0.f;
    for (int i = 0; i < H; ++i) s = fmaf(v[i], Zn[k * H + i], s);
    lg[o] = s;
  }
  __syncthreads();
  if (o < 2) {
    float* l0 = &lg[o * 64];
    float* p0 = &pr[o * 64];
    float mx = l0[0];
    for (int k = 1; k < 64; ++k) mx = fmaxf(mx, l0[k]);
    float sum = 0.f;
    for (int k = 0; k < 64; ++k) { float e = __expf(l0[k] - mx); p0[k] = e; sum += e; }
    float inv = 1.f / sum;
    for (int k = 0; k < 64; ++k) p0[k] *= inv;
  }
  __syncthreads();
  {
    float s1 = 0.f, s2 = 0.f;
    for (int k = 0; k < 64; ++k) {
      float z = Zn[k * H + o];
      s1 = fmaf(pr[k], z, s1);
      s2 = fmaf(pr[64 + k], z, s2);
    }
    s1 = 1.f / (1.f + __expf(-s1));
    s2 = 1.f / (1.f + __expf(-s2));
    sv[o] = s1 * s2;
  }
  __syncthreads();
  if (o == 0) {
    float d0 = 0.f, d1 = 0.f, d2 = 0.f;
    for (int i = 0; i < H; ++i) { d0 += re[i] * go[i]; d1 += re[i] * rs[i]; d2 += re[i] * sv[i]; }
    float mx = fmaxf(d0, fmaxf(d1, d2));
    float e0 = __expf(d0 - mx), e1 = __expf(d1 - mx), e2 = __expf(d2 - mx);
    float inv = 1.f / (e0 + e1 + e2);
    att[0] = e0 * inv; att[1] = e1 * inv; att[2] = e2 * inv;
  }
  __syncthreads();
  float va = att[0] * go[o] + att[1] * rs[o] + att[2] * sv[o];

  float p = 0.f;
  p = fmaf(hf[o],       fcW[o],       p);
  p = fmaf(hf[128 + o], fcW[128 + o], p);
  p = fmaf(hf[256 + o], fcW[256 + o], p);
  p = fmaf(tf[o],       fcW[384 + o], p);
  p = fmaf(tf[128 + o], fcW[512 + o], p);
  p = fmaf(tf[256 + o], fcW[640 + o], p);
  p = fmaf(re[o],       fcW[768 + o], p);
  p = fmaf(va,          fcW[896 + o], p);
  red[o] = p;
  __syncthreads();
  if (o == 0) {
    float s = 0.f;
    for (int i = 0; i < 128; ++i) s += red[i];
    out[b] = s + fcB[0];
  }
}

extern "C" void kernel_launch(void* const* d_in, const int* in_sizes, int n_in,
                              void* d_out, int out_size, void* d_ws, size_t ws_size,
                              hipStream_t stream) {
  const float* x        = (const float*)d_in[0];
  const float* W_rel    = (const float*)d_in[1];
  const float* W_self   = (const float*)d_in[2];
  const float* rel_tb   = (const float*)d_in[3];
  const float* Zn       = (const float*)d_in[4];
  const float* proj_W   = (const float*)d_in[5];
  const float* proj_b   = (const float*)d_in[6];
  const float* fc_W     = (const float*)d_in[7];
  const float* fc_b     = (const float*)d_in[8];
  const float* rep_seq  = (const float*)d_in[9];
  const int* src      = (const int*)d_in[10];
  const int* dst      = (const int*)d_in[11];
  const int* etype    = (const int*)d_in[12];
  const int* graph_id = (const int*)d_in[13];
  const int* head_ids = (const int*)d_in[14];
  const int* tail_ids = (const int*)d_in[15];
  const int* rel_lab  = (const int*)d_in[16];
  float* out = (float*)d_out;

  // workspace carve (~115 MB), all 16B aligned
  char* w = (char*)d_ws;
  unsigned short* G  = (unsigned short*)w; w += (size_t)N_NODES * NW * 2;              // 73.7 MB
  unsigned short* hb = (unsigned short*)w; w += (size_t)(NL + 1) * N_NODES * H * 2;    // 32.8 MB
  unsigned short* Bt = (unsigned short*)w; w += (size_t)NL * NW * H * 2;               // 0.88 MB
  int* row_ptr2 = (int*)w;  w += (size_t)(NBIN2 + 8) * 4;                              // 1.05 MB
  int* cursor   = (int*)w;  w += (size_t)NBIN2 * 4;                                    // 1.05 MB (scan-written)
  int* edge_off = (int*)w;  w += (size_t)NEDGE * 4;
  // zero region: cnt | gcount | gmean
  char* z = w;
  int* cnt     = (int*)w;   w += (size_t)NBIN2 * 4;                                    // 1.05 MB
  int* gcount  = (int*)w;   w += (size_t)32 * 4;
  float* gmean = (float*)w; w += (size_t)BSZ * NL * H * 4;
  size_t zbytes = (size_t)(w - z);

  hipMemsetAsync(z, 0, zbytes, stream);
  k_prep <<<7853, 256, 0, stream>>>(x, W_rel, W_self, dst, graph_id, hb, Bt, cnt, gcount);
  k_scan1<<<1, 1024, 0, stream>>>(cnt, row_ptr2, cursor);
  k_fill <<<NEDGE / 256, 256, 0, stream>>>(src, dst, etype, cursor, edge_off);

  for (int l = 0; l < NL; ++l) {
    const unsigned short* hp = hb + (size_t)l * N_NODES * H;
    unsigned short* hn = hb + (size_t)(l + 1) * N_NODES * H;
    k_gemm9 <<<dim3(N_NODES / 128, 9), 256, 0, stream>>>(hp, Bt + (size_t)l * NW * H, G);
    k_gather<<<N_NODES / 4, 256, 0, stream>>>(G, row_ptr2, edge_off, hn);
  }
  k_gmean<<<dim3(BSZ, NL, 8), 64, 0, stream>>>(hb, gmean);
  k_final<<<BSZ, H, 0, stream>>>(hb, gmean, gcount, rel_tb, Zn, proj_W, proj_b, fc_W, fc_b,
                                 rep_seq, head_ids, tail_ids, rel_lab, out);
  (void)in_sizes; (void)n_in; (void)out_size; (void)ws_size;
}

// Round 12
// 336.769 us; speedup vs baseline: 1.3743x; 1.3743x over previous
//
#include <hip/hip_runtime.h>

#define N_NODES 32000
#define NPG     1000
#define BSZ     32
#define NEDGE   512000
#define H       128
#define NL      3
#define NR      8
#define NW      1152    // 8*128 rel cols + 128 self cols
#define NBIN2   262144  // 32768 dst bins x 8 contention-splitting sub-bins

typedef __attribute__((ext_vector_type(8))) short short8;
typedef __attribute__((ext_vector_type(4))) float float4v;

__device__ __forceinline__ float bf2f(unsigned short u) {
  union { unsigned int i; float f; } v;
  v.i = ((unsigned int)u) << 16;
  return v.f;
}
__device__ __forceinline__ unsigned short f2bf(float f) {
  union { float f; unsigned int i; } v;
  v.f = f;
  unsigned int x = v.i;
  return (unsigned short)((x + 0x7FFFu + ((x >> 16) & 1u)) >> 16);  // RNE
}

// ---------------- fused prep: cvtX | cvtB | per-(dst,sub) count | graph hist ----------
__global__ __launch_bounds__(256) void k_prep(
    const float* __restrict__ x, const float* __restrict__ W_rel,
    const float* __restrict__ W_self, const int* __restrict__ dst,
    const int* __restrict__ graph_id,
    unsigned short* __restrict__ hb, unsigned short* __restrict__ Bt,
    int* __restrict__ cnt, int* __restrict__ gcount)
{
  const int b = blockIdx.x, t = threadIdx.x;
  if (b < 4000) {                       // x fp32 -> h0 bf16
    const size_t i = ((size_t)b * 256 + t) * 4;
    float4 v = *(const float4*)(x + i);
    ushort4 u = { f2bf(v.x), f2bf(v.y), f2bf(v.z), f2bf(v.w) };
    *(ushort4*)(hb + i) = u;
  } else if (b < 5728) {                // weights -> Bt9[l][n=0..1151][k] (transposed)
    const int g = (b - 4000) * 256 + t;  // 0..442367
    const int k = g & 127;
    const int n = (g >> 7) % NW;
    const int l = g / (NW * H);
    float v = (n < 1024) ? W_rel[(((size_t)l * NR + (n >> 7)) * H + k) * H + (n & 127)]
                         : W_self[((size_t)l * H + k) * H + (n - 1024)];
    Bt[(size_t)l * (NW * H) + (size_t)n * H + k] = f2bf(v);
  } else if (b < 7728) {                // per-(dst,sub) edge counts, 8-way de-contended
    const int bb = b - 5728;            // 0..1999
    const int e = bb * 256 + t;
    atomicAdd(&cnt[dst[e] * 8 + (bb & 7)], 1);
  } else {                              // graph histogram (125 blocks)
    __shared__ int hist[BSZ];
    if (t < BSZ) hist[t] = 0;
    __syncthreads();
    const int n = (b - 7728) * 256 + t;
    if (n < N_NODES) atomicAdd(&hist[graph_id[n]], 1);
    __syncthreads();
    if (t < BSZ) { int v = hist[t]; if (v) atomicAdd(&gcount[t], v); }
  }
}

// ---------------- 3-phase exclusive scan over NBIN2 bins (R7-proven shape) ----------
__global__ __launch_bounds__(256) void k_scanA(const int* __restrict__ cnt,
                                               int* __restrict__ bsum) {
  __shared__ int red[256];
  const int t = threadIdx.x;
  int4 v = *(const int4*)(cnt + blockIdx.x * 1024 + t * 4);
  red[t] = v.x + v.y + v.z + v.w;
  __syncthreads();
  for (int off = 128; off > 0; off >>= 1) {
    if (t < off) red[t] += red[t + off];
    __syncthreads();
  }
  if (t == 0) bsum[blockIdx.x] = red[0];
}

__global__ __launch_bounds__(256) void k_scanB(const int* __restrict__ bsum,
                                               int* __restrict__ boff) {
  __shared__ int v[256];
  const int t = threadIdx.x;  // 256 block sums
  v[t] = bsum[t];
  __syncthreads();
  if (t == 0) {
    int r = 0;
    for (int i = 0; i < 256; ++i) { int c = v[i]; v[i] = r; r += c; }
  }
  __syncthreads();
  boff[t] = v[t];
}

__global__ __launch_bounds__(256) void k_scanC(const int* __restrict__ cnt,
                                               const int* __restrict__ boff,
                                               int* __restrict__ row_ptr2,
                                               int* __restrict__ cursor) {
  __shared__ int ts[256];
  const int t = threadIdx.x;
  const int base = blockIdx.x * 1024 + t * 4;
  int4 v = *(const int4*)(cnt + base);
  const int s = v.x + v.y + v.z + v.w;
  ts[t] = s;
  __syncthreads();
  for (int off = 1; off < 256; off <<= 1) {   // inclusive Hillis-Steele
    int val = (t >= off) ? ts[t - off] : 0;
    __syncthreads();
    ts[t] += val;
    __syncthreads();
  }
  int ex = ts[t] - s + boff[blockIdx.x];
  int4 w = { ex, ex + v.x, ex + v.x + v.y, ex + v.x + v.y + v.z };
  *(int4*)(row_ptr2 + base) = w;
  *(int4*)(cursor + base) = w;
}

// ---------------- fill: edge_off[p] = src*1152 + etype*128, grouped by (dst,sub) ----
__global__ void k_fill(const int* __restrict__ src, const int* __restrict__ dst,
                       const int* __restrict__ etype, int* __restrict__ cursor,
                       int* __restrict__ edge_off) {
  int e = blockIdx.x * blockDim.x + threadIdx.x;
  if (e < NEDGE) {
    int p = atomicAdd(&cursor[dst[e] * 8 + (blockIdx.x & 7)], 1);
    edge_off[p] = src[e] * NW + etype[e] * H;
  }
}

// ---------------- GEMM9: G = h @ [Wrel(8) | Wself]  (M=32000, K=128, N=1152) --------
__global__ __launch_bounds__(256) void k_gemm9(
    const unsigned short* __restrict__ Ah,   // [32000,128] bf16
    const unsigned short* __restrict__ Bt,   // [1152,128]  bf16
    unsigned short* __restrict__ G)          // [32000,1152] bf16
{
  __shared__ unsigned short lds_a[128 * 136];
  __shared__ unsigned short lds_b[128 * 136];
  const int tid  = threadIdx.x;
  const int wave = tid >> 6, lane = tid & 63;
  const int l15 = lane & 15, quad = lane >> 4;
  const int m0 = blockIdx.x * 128;
  const int n0 = blockIdx.y * 128;
  const int mb = (wave & 1) * 64;
  const int nb = (wave >> 1) * 64;

  #pragma unroll
  for (int s = 0; s < 8; ++s) {
    int f  = s * 256 + tid;
    int m  = f >> 4;
    int ko = (f & 15) * 8;
    *(uint4*)(lds_a + m * 136 + ko) = *(const uint4*)(Ah + (size_t)(m0 + m) * H + ko);
    *(uint4*)(lds_b + m * 136 + ko) = *(const uint4*)(Bt + (size_t)(n0 + m) * H + ko);
  }
  __syncthreads();

  float4v acc[4][4];
  #pragma unroll
  for (int i = 0; i < 4; ++i)
    #pragma unroll
    for (int j = 0; j < 4; ++j) acc[i][j] = (float4v){0.f, 0.f, 0.f, 0.f};

  #pragma unroll
  for (int ks = 0; ks < 4; ++ks) {
    const int ko = ks * 32 + quad * 8;
    short8 afr[4], bfr[4];
    #pragma unroll
    for (int i = 0; i < 4; ++i)
      afr[i] = *(const short8*)(lds_a + (mb + i * 16 + l15) * 136 + ko);
    #pragma unroll
    for (int j = 0; j < 4; ++j)
      bfr[j] = *(const short8*)(lds_b + (nb + j * 16 + l15) * 136 + ko);
    #pragma unroll
    for (int i = 0; i < 4; ++i)
      #pragma unroll
      for (int j = 0; j < 4; ++j)
        acc[i][j] = __builtin_amdgcn_mfma_f32_16x16x32_bf16(afr[i], bfr[j], acc[i][j], 0, 0, 0);
  }

  // repack -> coalesced uint4 stores. D: row=quad*4+r, col=l15.
  __syncthreads();
  #pragma unroll
  for (int i = 0; i < 4; ++i)
    #pragma unroll
    for (int j = 0; j < 4; ++j)
      #pragma unroll
      for (int r = 0; r < 4; ++r)
        lds_a[(mb + i * 16 + quad * 4 + r) * 136 + nb + j * 16 + l15] = f2bf(acc[i][j][r]);
  __syncthreads();
  #pragma unroll
  for (int s = 0; s < 8; ++s) {
    int f  = s * 256 + tid;
    int m  = f >> 4;
    int ko = (f & 15) * 8;
    *(uint4*)(G + (size_t)(m0 + m) * NW + n0 + ko) = *(const uint4*)(lds_a + m * 136 + ko);
  }
}

// ---------------- edge gather: half-wave edge split, uint2 row loads --------
// h_next[n] = relu(G[n,1024:] + sum_e G[edge_off[e], :128])
// per-node edge range = [row_ptr2[n*8], row_ptr2[n*8+8]) (dst-major sub-bins).
__global__ __launch_bounds__(256) void k_gather(
    const unsigned short* __restrict__ G, const int* __restrict__ row_ptr2,
    const int* __restrict__ edge_off, unsigned short* __restrict__ Hnext)
{
  const int node = blockIdx.x * 4 + (threadIdx.x >> 6);
  const int lane = threadIdx.x & 63;
  const int half = lane >> 5;
  const int li   = lane & 31;
  const int c0   = li * 4;
  const int beg = row_ptr2[node << 3];
  const int end = row_ptr2[(node << 3) + 8];
  float s0 = 0.f, s1 = 0.f, s2 = 0.f, s3 = 0.f;
  if (half == 0) {   // self term counted once
    uint2 u = *(const uint2*)(G + (size_t)node * NW + 1024 + c0);
    s0 = bf2f((unsigned short)(u.x & 0xffff));
    s1 = bf2f((unsigned short)(u.x >> 16));
    s2 = bf2f((unsigned short)(u.y & 0xffff));
    s3 = bf2f((unsigned short)(u.y >> 16));
  }
#define ACC4(u) { \
    s0 += bf2f((unsigned short)((u).x & 0xffff)); \
    s1 += bf2f((unsigned short)((u).x >> 16));    \
    s2 += bf2f((unsigned short)((u).y & 0xffff)); \
    s3 += bf2f((unsigned short)((u).y >> 16)); }
  int e = beg + half;
  for (; e + 6 < end; e += 8) {   // 4 rows in flight per half = 8 per wave
    int o0 = edge_off[e],     o1 = edge_off[e + 2];
    int o2 = edge_off[e + 4], o3 = edge_off[e + 6];
    uint2 u0 = *(const uint2*)(G + o0 + c0);
    uint2 u1 = *(const uint2*)(G + o1 + c0);
    uint2 u2 = *(const uint2*)(G + o2 + c0);
    uint2 u3 = *(const uint2*)(G + o3 + c0);
    ACC4(u0) ACC4(u1) ACC4(u2) ACC4(u3)
  }
  for (; e < end; e += 2) {
    int o = edge_off[e];
    uint2 u = *(const uint2*)(G + o + c0);
    ACC4(u)
  }
#undef ACC4
  s0 += __shfl_xor(s0, 32);
  s1 += __shfl_xor(s1, 32);
  s2 += __shfl_xor(s2, 32);
  s3 += __shfl_xor(s3, 32);
  if (half == 0) {
    uint2 w;
    w.x = (unsigned int)f2bf(fmaxf(s0, 0.f)) | ((unsigned int)f2bf(fmaxf(s1, 0.f)) << 16);
    w.y = (unsigned int)f2bf(fmaxf(s2, 0.f)) | ((unsigned int)f2bf(fmaxf(s3, 0.f)) << 16);
    *(uint2*)(Hnext + (size_t)node * H + c0) = w;
  }
}

// ---------------- per-graph partial mean from bf16 h (8-way split + float atomics) ----
__global__ void k_gmean(const unsigned short* __restrict__ hb, float* __restrict__ gmean)
{
  const int g = blockIdx.x, l = blockIdx.y, c = blockIdx.z, t = threadIdx.x;  // 64
  const unsigned short* base =
      hb + ((size_t)(l + 1) * N_NODES + (size_t)g * NPG + (size_t)c * (NPG / 8)) * H + t * 2;
  float sx = 0.f, sy = 0.f;
  for (int i = 0; i < 125; ++i) {
    unsigned int u = *(const unsigned int*)(base + (size_t)i * H);
    sx += bf2f((unsigned short)(u & 0xffff));
    sy += bf2f((unsigned short)(u >> 16));
  }
  float* gp = gmean + (size_t)g * (NL * H) + l * H + t * 2;
  atomicAdd(gp, sx);
  atomicAdd(gp + 1, sy);
}

// ---------------- readout ----------------
__global__ __launch_bounds__(128) void k_final(
    const unsigned short* __restrict__ hb, const float* __restrict__ gmean,
    const int* __restrict__ gcount,
    const float* __restrict__ rel_tb, const float* __restrict__ Zn,
    const float* __restrict__ projW, const float* __restrict__ projB,
    const float* __restrict__ fcW, const float* __restrict__ fcB,
    const float* __restrict__ repSeq,
    const int* __restrict__ head_ids, const int* __restrict__ tail_ids,
    const int* __restrict__ rel_lab, float* __restrict__ out)
{
  const int b = blockIdx.x;
  const int o = threadIdx.x;   // 128
  __shared__ float gm[384], hf[384], tf[384];
  __shared__ float go[128], ho[128], t_o[128], re[128], rs[128], sv[128];
  __shared__ float lg[128], pr[128], red[128], att[3];

  const int hid = head_ids[b], tlid = tail_ids[b], rl = rel_lab[b];
  const float cinv = 1.f / (float)gcount[b];
  #pragma unroll
  for (int l = 0; l < NL; ++l) {
    gm[l * H + o] = gmean[(size_t)b * (NL * H) + l * H + o] * cinv;
    hf[l * H + o] = bf2f(hb[((size_t)(l + 1) * N_NODES + hid) * H + o]);
    tf[l * H + o] = bf2f(hb[((size_t)(l + 1) * N_NODES + tlid) * H + o]);
  }
  re[o] = rel_tb[rl * H + o];
  rs[o] = repSeq[b * H + o];
  __syncthreads();

  float pb = projB[o];
  float sg = pb, sh = pb, st = pb;
  for (int i = 0; i < NL * H; ++i) {
    float wv = projW[i * H + o];
    sg = fmaf(gm[i], wv, sg);
    sh = fmaf(hf[i], wv, sh);
    st = fmaf(tf[i], wv, st);
  }
  go[o] = (sg > 0.f) ? sg : 0.01f * sg;
  ho[o] = sh;
  t_o[o] = st;
  __syncthreads();

  {
    const int k = o & 63;
    const float* v = (o < 64) ? ho : t_o;
    float s = 0.f;
    for (int i = 0; i < H; ++i) s = fmaf(v[i], Zn[k * H + i], s);
    lg[o] = s;
  }
  __syncthreads();
  if (o < 2) {
    float* l0 = &lg[o * 64];
    float* p0 = &pr[o * 64];
    float mx = l0[0];
    for (int k = 1; k < 64; ++k) mx = fmaxf(mx, l0[k]);
    float sum = 0.f;
    for (int k = 0; k < 64; ++k) { float e = __expf(l0[k] - mx); p0[k] = e; sum += e; }
    float inv = 1.f / sum;
    for (int k = 0; k < 64; ++k) p0[k] *= inv;
  }
  __syncthreads();
  {
    float s1 = 0.f, s2 = 0.f;
    for (int k = 0; k < 64; ++k) {
      float z = Zn[k * H + o];
      s1 = fmaf(pr[k], z, s1);
      s2 = fmaf(pr[64 + k], z, s2);
    }
    s1 = 1.f / (1.f + __expf(-s1));
    s2 = 1.f / (1.f + __expf(-s2));
    sv[o] = s1 * s2;
  }
  __syncthreads();
  if (o == 0) {
    float d0 = 0.f, d1 = 0.f, d2 = 0.f;
    for (int i = 0; i < H; ++i) { d0 += re[i] * go[i]; d1 += re[i] * rs[i]; d2 += re[i] * sv[i]; }
    float mx = fmaxf(d0, fmaxf(d1, d2));
    float e0 = __expf(d0 - mx), e1 = __expf(d1 - mx), e2 = __expf(d2 - mx);
    float inv = 1.f / (e0 + e1 + e2);
    att[0] = e0 * inv; att[1] = e1 * inv; att[2] = e2 * inv;
  }
  __syncthreads();
  float va = att[0] * go[o] + att[1] * rs[o] + att[2] * sv[o];

  float p = 0.f;
  p = fmaf(hf[o],       fcW[o],       p);
  p = fmaf(hf[128 + o], fcW[128 + o], p);
  p = fmaf(hf[256 + o], fcW[256 + o], p);
  p = fmaf(tf[o],       fcW[384 + o], p);
  p = fmaf(tf[128 + o], fcW[512 + o], p);
  p = fmaf(tf[256 + o], fcW[640 + o], p);
  p = fmaf(re[o],       fcW[768 + o], p);
  p = fmaf(va,          fcW[896 + o], p);
  red[o] = p;
  __syncthreads();
  if (o == 0) {
    float s = 0.f;
    for (int i = 0; i < 128; ++i) s += red[i];
    out[b] = s + fcB[0];
  }
}

extern "C" void kernel_launch(void* const* d_in, const int* in_sizes, int n_in,
                              void* d_out, int out_size, void* d_ws, size_t ws_size,
                              hipStream_t stream) {
  const float* x        = (const float*)d_in[0];
  const float* W_rel    = (const float*)d_in[1];
  const float* W_self   = (const float*)d_in[2];
  const float* rel_tb   = (const float*)d_in[3];
  const float* Zn       = (const float*)d_in[4];
  const float* proj_W   = (const float*)d_in[5];
  const float* proj_b   = (const float*)d_in[6];
  const float* fc_W     = (const float*)d_in[7];
  const float* fc_b     = (const float*)d_in[8];
  const float* rep_seq  = (const float*)d_in[9];
  const int* src      = (const int*)d_in[10];
  const int* dst      = (const int*)d_in[11];
  const int* etype    = (const int*)d_in[12];
  const int* graph_id = (const int*)d_in[13];
  const int* head_ids = (const int*)d_in[14];
  const int* tail_ids = (const int*)d_in[15];
  const int* rel_lab  = (const int*)d_in[16];
  float* out = (float*)d_out;

  // workspace carve (~115 MB), all 16B aligned
  char* w = (char*)d_ws;
  unsigned short* G  = (unsigned short*)w; w += (size_t)N_NODES * NW * 2;              // 73.7 MB
  unsigned short* hb = (unsigned short*)w; w += (size_t)(NL + 1) * N_NODES * H * 2;    // 32.8 MB
  unsigned short* Bt = (unsigned short*)w; w += (size_t)NL * NW * H * 2;               // 0.88 MB
  int* row_ptr2 = (int*)w;  w += (size_t)(NBIN2 + 8) * 4;                              // 1.05 MB
  int* cursor   = (int*)w;  w += (size_t)NBIN2 * 4;                                    // 1.05 MB (scan-written)
  int* edge_off = (int*)w;  w += (size_t)NEDGE * 4;
  int* bsum     = (int*)w;  w += (size_t)256 * 4;
  int* boff     = (int*)w;  w += (size_t)256 * 4;
  // zero region: cnt | gcount | gmean
  char* z = w;
  int* cnt     = (int*)w;   w += (size_t)NBIN2 * 4;                                    // 1.05 MB
  int* gcount  = (int*)w;   w += (size_t)32 * 4;
  float* gmean = (float*)w; w += (size_t)BSZ * NL * H * 4;
  size_t zbytes = (size_t)(w - z);

  hipMemsetAsync(z, 0, zbytes, stream);
  k_prep <<<7853, 256, 0, stream>>>(x, W_rel, W_self, dst, graph_id, hb, Bt, cnt, gcount);
  k_scanA<<<NBIN2 / 1024, 256, 0, stream>>>(cnt, bsum);
  k_scanB<<<1, 256, 0, stream>>>(bsum, boff);
  k_scanC<<<NBIN2 / 1024, 256, 0, stream>>>(cnt, boff, row_ptr2, cursor);
  k_fill <<<NEDGE / 256, 256, 0, stream>>>(src, dst, etype, cursor, edge_off);

  for (int l = 0; l < NL; ++l) {
    const unsigned short* hp = hb + (size_t)l * N_NODES * H;
    unsigned short* hn = hb + (size_t)(l + 1) * N_NODES * H;
    k_gemm9 <<<dim3(N_NODES / 128, 9), 256, 0, stream>>>(hp, Bt + (size_t)l * NW * H, G);
    k_gather<<<N_NODES / 4, 256, 0, stream>>>(G, row_ptr2, edge_off, hn);
  }
  k_gmean<<<dim3(BSZ, NL, 8), 64, 0, stream>>>(hb, gmean);
  k_final<<<BSZ, H, 0, stream>>>(hb, gmean, gcount, rel_tb, Zn, proj_W, proj_b, fc_W, fc_b,
                                 rep_seq, head_ids, tail_ids, rel_lab, out);
  (void)in_sizes; (void)n_in; (void)out_size; (void)ws_size;
}